// Round 1
// baseline (4817.632 us; speedup 1.0000x reference)
//
#include <hip/hip_runtime.h>

// LatentExpander: 2-layer LSTM (H=128), B=512, SEQ=1024, out L=64.
// Inputs fp32, OUTPUT fp32. Single persistent kernel, no workspace.
// 32 blocks x 512 threads; 16 batch rows/block. ALL MFMA operands fp16
// (4x less rounding than bf16, same MFMA rate); fp32 accumulators/state.
// Recurrent weights fp32->fp16 in VGPR B-frags (B[k][n]=W[n][k], 8 contig k
// of a W row). Prologue computes xz / h-init / c-init via MFMA from an LDS
// z-tile. h-state in LDS fp16 (h0 rows: [h0(128)|h_prev(64)], stride 400 B;
// h1 rows: 128 cols, stride 272 B), double-buffered. Wave w owns gate cols
// {g*128+16w..+16} for all 4 gates -> c/h update wave-local. 3 barriers/step.
//
// R1 changes vs 5055us baseline:
//  - sigm_/tanh_ use v_rcp_f32 instead of full-precision div sequences
//    (~halves epilogue VALU, frees div temps/vcc in hottest region)
//  - out-proj writes h_t to a 2-step LDS buffer; coalesced f32x4 flush every
//    odd step (removes per-step global store from the barrier-adjacent path;
//    vmcnt(0) drain before barriers becomes free)
//  - layer-1 bias held in 4 VGPRs instead of per-step LDS b128 read
//
// MFMA 16x16x32 layout anchors (HW-verified; dtype-independent on gfx950):
//   A: lane holds A[m=l&15][k=(l>>4)*8+e]   (8 contig k, row-major LDS read)
//   B: lane holds B[k=(l>>4)*8+e][n=l&15]   = W[n][k], 8 contig k of row n
//   C/D: lane holds D[row=(l>>4)*4+r][col=l&15]

#define DI __device__ __forceinline__

typedef float f32x4 __attribute__((ext_vector_type(4)));
typedef _Float16 h16x4 __attribute__((ext_vector_type(4)));
typedef _Float16 h16x8 __attribute__((ext_vector_type(8)));

// fast sigmoid: 1 v_exp + 1 v_rcp (+mul/add). rcp is ~1ulp; error << fp16
// MFMA rounding already present in the gates.
DI float sigm_(float x) {
  float e = __expf(-x);
  return __builtin_amdgcn_rcpf(1.0f + e);
}
// fast tanh: (1-e)/(1+e), e=exp(-2|x|), division via v_rcp.
DI float tanh_(float x) {
  float ax = __builtin_fabsf(x);
  float e  = __expf(-2.0f * ax);
  float r  = (1.0f - e) * __builtin_amdgcn_rcpf(1.0f + e);
  return __builtin_copysignf(r, x);
}
// load 8 consecutive fp32, round (RNE) to fp16 frag
DI h16x8 cvt8h(const float* __restrict__ p) {
  f32x4 a = *(const f32x4*)p;
  f32x4 b = *(const f32x4*)(p + 4);
  _Float16 t[8];
#pragma unroll
  for (int i = 0; i < 4; ++i) {
    t[i]     = (_Float16)a[i];
    t[4 + i] = (_Float16)b[i];
  }
  return *(h16x8*)t;
}

// ---------------- LDS map (bytes) ----------------
// H0: 2 bufs x 16 rows x 400 B (cols 0..127 h0, 128..191 h_prev) = 12800
// H1: 2 bufs x 16 x 272 = 8704                         [12800, 21504)
// WO: out-proj B-frag stream, 16 frags x 64 lanes x 16 = [21504, 37888)
// XZ: fp16, 512 thr x 32 B = 16384                      [37888, 54272)
// OB: out ring, 2 steps x 16 rows x 64 f32 = 8192       [54272, 62464)
// AZ: prologue z-tile 16 x 528 = 8448 — OVERLAPS XZ region (barrier-ordered)
#define L_H0 0
#define L_H1 12800
#define L_WO 21504
#define L_XZ 37888
#define L_OB 54272
#define L_AZ 37888
#define L_TOT 62464
static_assert(L_TOT <= 65536, "LDS budget");

__global__ __launch_bounds__(512) void k_main(
    const float* __restrict__ z,
    const float* __restrict__ W_init_h, const float* __restrict__ b_init_h,
    const float* __restrict__ W_init_c, const float* __restrict__ b_init_c,
    const float* __restrict__ W_ih0, const float* __restrict__ W_hh0,
    const float* __restrict__ b_ih0, const float* __restrict__ b_hh0,
    const float* __restrict__ W_ih1, const float* __restrict__ W_hh1,
    const float* __restrict__ b_ih1, const float* __restrict__ b_hh1,
    const float* __restrict__ W_out, const float* __restrict__ b_out,
    float* __restrict__ out) {
  __shared__ __align__(16) unsigned char smem[L_TOT];
  const int tid = threadIdx.x;
  const int w = tid >> 6, l = tid & 63;
  const int l15 = l & 15, l4 = l >> 4;
  const int bl = blockIdx.x, b0 = bl << 4;
  const int col = 16 * w + l15;                 // owned gate/hidden col 0..127

  // ---------- prologue stage 1: fills ----------
  f32x4 bvr;                                    // layer-1 bias, lives in VGPR
  {
    // z tile -> AZ fp16: rows m=0..15, 256 cols, stride 528 B
    int zm = tid >> 5, zk = (tid & 31) * 8;
    *(h16x8*)(smem + L_AZ + zm * 528 + zk * 2) = cvt8h(z + (b0 + zm) * 256 + zk);
    // W_out -> per-wave frag stream: frag f=kc*4+wv, lane l holds
    // W_out[n=16*wv+(l&15)][k=kc*32+(l>>4)*8 .. +8]
    for (int i = tid; i < 1024; i += 512) {
      int li = i & 63, f = i >> 6;
      int kc = f >> 2, wv = f & 3;
      int n = 16 * wv + (li & 15), k0 = kc * 32 + ((li >> 4) & 3) * 8;
      *(h16x8*)(smem + L_WO + i * 16) = cvt8h(W_out + n * 128 + k0);
    }
    // layer-1 bias per-thread fp32 (registers)
#pragma unroll
    for (int g = 0; g < 4; ++g)
      bvr[g] = b_ih1[g * 128 + col] + b_hh1[g * 128 + col];
    // zero h_prev cols (128..191) of H0 buffer 0
    if (tid < 256) {
      int r2 = tid >> 4, c2 = (tid & 15) * 4;
      h16x4 zz = {(_Float16)0, (_Float16)0, (_Float16)0, (_Float16)0};
      *(h16x4*)(smem + L_H0 + r2 * 400 + 256 + c2 * 2) = zz;
    }
  }
  __syncthreads();                              // AZ / WO visible

  // ---------- prologue stage 2: MFMA prep GEMMs (reads AZ) ----------
  // xz[m][n] = z[m,:]·W_ih0[n,64:] + b_ih0[n]+b_hh0[n]   (n = g*128+col)
  // h/c init[m][layer*128+col] = z[m,:]·W_init_{h,c}[n,:] + b
  float c0i[4], c1i[4];
  f32x4 xza[4];
  {
    f32x4 ha[2], ca[2];
#pragma unroll
    for (int g = 0; g < 4; ++g) {
      float b = b_ih0[g * 128 + col] + b_hh0[g * 128 + col];
      f32x4 a = {b, b, b, b}; xza[g] = a;
    }
#pragma unroll
    for (int layer = 0; layer < 2; ++layer) {
      float bh = b_init_h[layer * 128 + col];
      float bc = b_init_c[layer * 128 + col];
      f32x4 ah = {bh, bh, bh, bh}; ha[layer] = ah;
      f32x4 ac = {bc, bc, bc, bc}; ca[layer] = ac;
    }
#pragma unroll
    for (int kc = 0; kc < 8; ++kc) {
      h16x8 az = *(const h16x8*)(smem + L_AZ + l15 * 528 + kc * 64 + l4 * 16);
      int kofs = kc * 32 + l4 * 8;
#pragma unroll
      for (int g = 0; g < 4; ++g) {
        h16x8 bz = cvt8h(W_ih0 + (g * 128 + col) * 320 + 64 + kofs);
        xza[g] = __builtin_amdgcn_mfma_f32_16x16x32_f16(az, bz, xza[g], 0, 0, 0);
      }
#pragma unroll
      for (int layer = 0; layer < 2; ++layer) {
        h16x8 bh = cvt8h(W_init_h + (layer * 128 + col) * 256 + kofs);
        ha[layer] = __builtin_amdgcn_mfma_f32_16x16x32_f16(az, bh, ha[layer], 0, 0, 0);
        h16x8 bc = cvt8h(W_init_c + (layer * 128 + col) * 256 + kofs);
        ca[layer] = __builtin_amdgcn_mfma_f32_16x16x32_f16(az, bc, ca[layer], 0, 0, 0);
      }
    }
    // h-init -> H0/H1 buffer 0 ; c stays in registers
#pragma unroll
    for (int r = 0; r < 4; ++r) {
      int m = l4 * 4 + r;
      *(_Float16*)(smem + L_H0 + m * 400 + col * 2) = (_Float16)ha[0][r];
      *(_Float16*)(smem + L_H1 + m * 272 + col * 2) = (_Float16)ha[1][r];
    }
#pragma unroll
    for (int r = 0; r < 4; ++r) { c0i[r] = ca[0][r]; c1i[r] = ca[1][r]; }
  }
  __syncthreads();                              // all AZ reads done
  // xz -> LDS fp16 (overwrites AZ region — safe after barrier)
#pragma unroll
  for (int g = 0; g < 4; ++g) {
    _Float16 t[4];
#pragma unroll
    for (int r = 0; r < 4; ++r) t[r] = (_Float16)xza[g][r];
    *(h16x4*)(smem + L_XZ + g * 4096 + tid * 8) = *(h16x4*)t;
  }

  // ---------- persistent weights into VGPR B-frags (fp16) ----------
  // L0 (K=192): k<128 -> W_hh0[n][k] (h0_old); k in [128,192) -> W_ih0[n][k-128] (h_prev)
  // L1 (K=256): k<128 -> W_ih1[n][k] (h0_new); k>=128 -> W_hh1[n][k-128] (h1_old)
  h16x8 wf[56];
#pragma unroll
  for (int kc = 0; kc < 6; ++kc)
#pragma unroll
    for (int g = 0; g < 4; ++g) {
      int n = g * 128 + col, k0 = kc * 32 + l4 * 8;
      const float* src = (k0 < 128) ? (W_hh0 + n * 128 + k0)
                                    : (W_ih0 + n * 320 + (k0 - 128));
      wf[kc * 4 + g] = cvt8h(src);
    }
#pragma unroll
  for (int kc = 0; kc < 8; ++kc)
#pragma unroll
    for (int g = 0; g < 4; ++g) {
      int n = g * 128 + col, k0 = kc * 32 + l4 * 8;
      const float* src = (k0 < 128) ? (W_ih1 + n * 128 + k0)
                                    : (W_hh1 + n * 128 + (k0 - 128));
      wf[24 + kc * 4 + g] = cvt8h(src);
    }

  float bo = (w < 4) ? b_out[col] : 0.0f;
  float c0r[4], c1r[4];
#pragma unroll
  for (int r = 0; r < 4; ++r) { c0r[r] = c0i[r]; c1r[r] = c1i[r]; }
  __syncthreads();                              // h-init / xz visible

  // ---------- time loop ----------
  for (int t = 0; t < 1024; ++t) {
    const int p = t & 1;
    const int h0r = L_H0 + p * 6400, h0w = L_H0 + 6400 - p * 6400;
    const int h1r = L_H1 + p * 4352, h1w = L_H1 + 4352 - p * 4352;

    // === layer 0: gates = [h0_old | h_prev] x W + xz ===
    f32x4 acc[4];
#pragma unroll
    for (int g = 0; g < 4; ++g) {
      h16x4 xv = *(const h16x4*)(smem + L_XZ + g * 4096 + tid * 8);
      f32x4 a;
#pragma unroll
      for (int r = 0; r < 4; ++r) a[r] = (float)xv[r];
      acc[g] = a;
    }
#pragma unroll
    for (int kc = 0; kc < 6; ++kc) {
      h16x8 af = *(const h16x8*)(smem + h0r + l15 * 400 + kc * 64 + l4 * 16);
#pragma unroll
      for (int g = 0; g < 4; ++g)
        acc[g] = __builtin_amdgcn_mfma_f32_16x16x32_f16(af, wf[kc * 4 + g],
                                                        acc[g], 0, 0, 0);
    }
#pragma unroll
    for (int r = 0; r < 4; ++r) {
      float ig = sigm_(acc[0][r]), fg = sigm_(acc[1][r]);
      float gg = tanh_(acc[2][r]), og = sigm_(acc[3][r]);
      c0r[r] = fg * c0r[r] + ig * gg;
      *(_Float16*)(smem + h0w + (l4 * 4 + r) * 400 + col * 2) =
          (_Float16)(og * tanh_(c0r[r]));
    }
    __syncthreads();                            // h0(t) visible

    // === layer 1: gates = [h0_new | h1_old] x W + (b_ih1+b_hh1) ===
#pragma unroll
    for (int g = 0; g < 4; ++g) {
      f32x4 a = {bvr[g], bvr[g], bvr[g], bvr[g]};
      acc[g] = a;
    }
#pragma unroll
    for (int kc = 0; kc < 8; ++kc) {
      h16x8 af = (kc < 4)
          ? *(const h16x8*)(smem + h0w + l15 * 400 + kc * 64 + l4 * 16)
          : *(const h16x8*)(smem + h1r + l15 * 272 + (kc - 4) * 64 + l4 * 16);
#pragma unroll
      for (int g = 0; g < 4; ++g)
        acc[g] = __builtin_amdgcn_mfma_f32_16x16x32_f16(af, wf[24 + kc * 4 + g],
                                                        acc[g], 0, 0, 0);
    }
#pragma unroll
    for (int r = 0; r < 4; ++r) {
      float ig = sigm_(acc[0][r]), fg = sigm_(acc[1][r]);
      float gg = tanh_(acc[2][r]), og = sigm_(acc[3][r]);
      c1r[r] = fg * c1r[r] + ig * gg;
      *(_Float16*)(smem + h1w + (l4 * 4 + r) * 272 + col * 2) =
          (_Float16)(og * tanh_(c1r[r]));
    }
    __syncthreads();                            // h1(t) visible

    // === out-proj (waves 0-3): h_t = tanh(h1_new x W_out^T + b_out) ===
    // writes LDS only: OB ring (this step's 16x64 f32) + h_prev fp16.
    if (w < 4) {
      f32x4 ao = {bo, bo, bo, bo};
#pragma unroll
      for (int kc = 0; kc < 4; ++kc) {
        h16x8 af  = *(const h16x8*)(smem + h1w + l15 * 272 + kc * 64 + l4 * 16);
        h16x8 bfr = *(const h16x8*)(smem + L_WO + ((kc * 4 + w) * 64 + l) * 16);
        ao = __builtin_amdgcn_mfma_f32_16x16x32_f16(af, bfr, ao, 0, 0, 0);
      }
#pragma unroll
      for (int r = 0; r < 4; ++r) {
        float v = tanh_(ao[r]);
        int m = l4 * 4 + r;
        *(float*)(smem + L_OB + m * 512 + p * 256 + col * 4) = v;  // out ring
        *(_Float16*)(smem + h0w + m * 400 + 256 + col * 2) =
            (_Float16)v;                                    // h_prev(t) fp16
      }
    }
    __syncthreads();                            // h_prev(t) + OB visible

    // === coalesced flush every other step: 2 t-steps x 16 rows x 64 j ===
    // thread tid owns f32x4 at OB linear idx tid*4; row m=tid>>5.
    // global runs are 512 B contiguous per batch row. Store retires during
    // next step's layer-0 compute (no barrier-adjacent vmcnt drain).
    if (p) {
      f32x4 vv = *(const f32x4*)(smem + L_OB + tid * 16);
      int m = tid >> 5, rem = (tid * 4) & 127;
      *(f32x4*)(out + (unsigned long long)(b0 + m) * 65536ull +
                (unsigned long long)(t - 1) * 64ull + rem) = vv;
    }
  }
}

// ---------------- launch ----------------
extern "C" void kernel_launch(void* const* d_in, const int* in_sizes, int n_in,
                              void* d_out, int out_size, void* d_ws, size_t ws_size,
                              hipStream_t stream) {
  (void)in_sizes; (void)n_in; (void)out_size; (void)d_ws; (void)ws_size;
  const float* z        = (const float*)d_in[0];
  // d_in[1] = seq_len (int scalar) == 1024, hardcoded
  const float* W_init_h = (const float*)d_in[2];
  const float* b_init_h = (const float*)d_in[3];
  const float* W_init_c = (const float*)d_in[4];
  const float* b_init_c = (const float*)d_in[5];
  const float* W_ih0 = (const float*)d_in[6];
  const float* W_hh0 = (const float*)d_in[7];
  const float* b_ih0 = (const float*)d_in[8];
  const float* b_hh0 = (const float*)d_in[9];
  const float* W_ih1 = (const float*)d_in[10];
  const float* W_hh1 = (const float*)d_in[11];
  const float* b_ih1 = (const float*)d_in[12];
  const float* b_hh1 = (const float*)d_in[13];
  const float* W_out = (const float*)d_in[14];
  const float* b_out = (const float*)d_in[15];
  float* out = (float*)d_out;

  k_main<<<dim3(32), dim3(512), 0, stream>>>(
      z, W_init_h, b_init_h, W_init_c, b_init_c,
      W_ih0, W_hh0, b_ih0, b_hh0, W_ih1, W_hh1, b_ih1, b_hh1,
      W_out, b_out, out);
}

// Round 2
// 3930.704 us; speedup vs baseline: 1.2256x; 1.2256x over previous
//
#include <hip/hip_runtime.h>

// LatentExpander: 2-layer LSTM (H=128), B=512, SEQ=1024, out L=64.
// Inputs fp32, OUTPUT fp32. Single persistent kernel, no workspace.
// 32 blocks x 512 threads; 16 batch rows/block. ALL MFMA operands fp16
// (4x less rounding than bf16, same MFMA rate); fp32 accumulators/state.
// Recurrent weights fp32->fp16 in VGPR B-frags (B[k][n]=W[n][k], 8 contig k
// of a W row). Prologue computes xz / h-init / c-init via MFMA from an LDS
// z-tile. h-state in LDS fp16 (h0 rows: [h0(128)|h_prev(64)], stride 400 B;
// h1 rows: 128 cols, stride 272 B), double-buffered. Wave w owns gate cols
// {g*128+16w..+16} for all 4 gates -> c/h update wave-local. 3 barriers/step.
//
// R2 changes vs 4690us R1 (rocprof: VGPR_Count=128 -> ALL 224 wf regs were
// spilled to scratch; WRITE_SIZE excess 14.1MB == 224*4B*16384thr):
//  - __launch_bounds__(512, 2): min 2 waves/EU -> 1 block/CU -> 256-VGPR
//    budget so wf[56] (224 regs) actually lives in registers.
//  - layer-1 bias + out bias in compact LDS tables (2KB+256B, broadcast
//    ds_read_b32/step) instead of 5 persistent VGPRs.
//  - time loop unrolled x2 with compile-time ping-pong (step<P>): LDS
//    double-buffer bases become immediates; addr regs minimal/remat-able.
//
// MFMA 16x16x32 layout anchors (HW-verified; dtype-independent on gfx950):
//   A: lane holds A[m=l&15][k=(l>>4)*8+e]   (8 contig k, row-major LDS read)
//   B: lane holds B[k=(l>>4)*8+e][n=l&15]   = W[n][k], 8 contig k of row n
//   C/D: lane holds D[row=(l>>4)*4+r][col=l&15]

#define DI __device__ __forceinline__

typedef float f32x4 __attribute__((ext_vector_type(4)));
typedef _Float16 h16x4 __attribute__((ext_vector_type(4)));
typedef _Float16 h16x8 __attribute__((ext_vector_type(8)));

// fast sigmoid: 1 v_exp + 1 v_rcp (+mul/add). rcp is ~1ulp; error << fp16
// MFMA rounding already present in the gates.
DI float sigm_(float x) {
  float e = __expf(-x);
  return __builtin_amdgcn_rcpf(1.0f + e);
}
// fast tanh: (1-e)/(1+e), e=exp(-2|x|), division via v_rcp.
DI float tanh_(float x) {
  float ax = __builtin_fabsf(x);
  float e  = __expf(-2.0f * ax);
  float r  = (1.0f - e) * __builtin_amdgcn_rcpf(1.0f + e);
  return __builtin_copysignf(r, x);
}
// load 8 consecutive fp32, round (RNE) to fp16 frag
DI h16x8 cvt8h(const float* __restrict__ p) {
  f32x4 a = *(const f32x4*)p;
  f32x4 b = *(const f32x4*)(p + 4);
  _Float16 t[8];
#pragma unroll
  for (int i = 0; i < 4; ++i) {
    t[i]     = (_Float16)a[i];
    t[4 + i] = (_Float16)b[i];
  }
  return *(h16x8*)t;
}

// ---------------- LDS map (bytes) ----------------
// H0: 2 bufs x 16 rows x 400 B (cols 0..127 h0, 128..191 h_prev) = 12800
// H1: 2 bufs x 16 x 272 = 8704                          [12800, 21504)
// WO: out-proj B-frag stream, 16 frags x 64 lanes x 16 = [21504, 37888)
// XZ: fp16, 512 thr x 32 B = 16384                      [37888, 54272)
// OB: out ring, 2 steps x 16 rows x 64 f32 = 8192       [54272, 62464)
// B1: compact layer-1 bias, 512 f32 = 2048              [62464, 64512)
// BO: out bias, 64 f32 = 256                            [64512, 64768)
// AZ: prologue z-tile 16 x 528 = 8448 — OVERLAPS XZ region (barrier-ordered)
#define L_H0 0
#define L_H1 12800
#define L_WO 21504
#define L_XZ 37888
#define L_OB 54272
#define L_B1 62464
#define L_BO 64512
#define L_AZ 37888
#define L_TOT 64768
static_assert(L_TOT <= 65536, "LDS budget");

// One time step; P = ping-pong phase (compile-time -> immediate LDS bases).
template <int P>
DI void lstm_step(unsigned char* smem, const h16x8 (&wf)[56],
                  f32x4& c0r, f32x4& c1r,
                  int a0off, int a1off, int xzoff, int v16,
                  int w0off, int w1off, int oboff,
                  int col, int wv, int t, float* outp0) {
  constexpr int h0r = L_H0 + P * 6400, h0w = L_H0 + 6400 - P * 6400;
  constexpr int h1r = L_H1 + P * 4352, h1w = L_H1 + 4352 - P * 4352;

  // === layer 0: gates = [h0_old | h_prev] x W + xz ===
  f32x4 acc[4];
#pragma unroll
  for (int g = 0; g < 4; ++g) {
    h16x4 xv = *(const h16x4*)(smem + L_XZ + g * 4096 + xzoff);
    f32x4 a;
#pragma unroll
    for (int r = 0; r < 4; ++r) a[r] = (float)xv[r];
    acc[g] = a;
  }
#pragma unroll
  for (int kc = 0; kc < 6; ++kc) {
    h16x8 af = *(const h16x8*)(smem + h0r + a0off + kc * 64);
#pragma unroll
    for (int g = 0; g < 4; ++g)
      acc[g] = __builtin_amdgcn_mfma_f32_16x16x32_f16(af, wf[kc * 4 + g],
                                                      acc[g], 0, 0, 0);
  }
#pragma unroll
  for (int r = 0; r < 4; ++r) {
    float ig = sigm_(acc[0][r]), fg = sigm_(acc[1][r]);
    float gg = tanh_(acc[2][r]), og = sigm_(acc[3][r]);
    c0r[r] = fg * c0r[r] + ig * gg;
    *(_Float16*)(smem + h0w + w0off + r * 400) = (_Float16)(og * tanh_(c0r[r]));
  }
  __syncthreads();                              // h0(t) visible

  // === layer 1: gates = [h0_new | h1_old] x W + (b_ih1+b_hh1) ===
#pragma unroll
  for (int g = 0; g < 4; ++g) {
    float bg = *(const float*)(smem + L_B1 + (g * 128 + col) * 4);
    f32x4 a = {bg, bg, bg, bg};
    acc[g] = a;
  }
#pragma unroll
  for (int kc = 0; kc < 8; ++kc) {
    h16x8 af = (kc < 4)
        ? *(const h16x8*)(smem + h0w + a0off + kc * 64)
        : *(const h16x8*)(smem + h1r + a1off + (kc - 4) * 64);
#pragma unroll
    for (int g = 0; g < 4; ++g)
      acc[g] = __builtin_amdgcn_mfma_f32_16x16x32_f16(af, wf[24 + kc * 4 + g],
                                                      acc[g], 0, 0, 0);
  }
#pragma unroll
  for (int r = 0; r < 4; ++r) {
    float ig = sigm_(acc[0][r]), fg = sigm_(acc[1][r]);
    float gg = tanh_(acc[2][r]), og = sigm_(acc[3][r]);
    c1r[r] = fg * c1r[r] + ig * gg;
    *(_Float16*)(smem + h1w + w1off + r * 272) = (_Float16)(og * tanh_(c1r[r]));
  }
  __syncthreads();                              // h1(t) visible

  // === out-proj (waves 0-3): h_t = tanh(h1_new x W_out^T + b_out) ===
  // writes LDS only: OB ring (this step's 16x64 f32) + h_prev fp16.
  if (wv < 4) {
    float bo = *(const float*)(smem + L_BO + col * 4);
    f32x4 ao = {bo, bo, bo, bo};
#pragma unroll
    for (int kc = 0; kc < 4; ++kc) {
      h16x8 af  = *(const h16x8*)(smem + h1w + a1off + kc * 64);
      h16x8 bfr = *(const h16x8*)(smem + L_WO + kc * 4096 + v16);
      ao = __builtin_amdgcn_mfma_f32_16x16x32_f16(af, bfr, ao, 0, 0, 0);
    }
#pragma unroll
    for (int r = 0; r < 4; ++r) {
      float v = tanh_(ao[r]);
      *(float*)(smem + L_OB + oboff + r * 512 + P * 256) = v;   // out ring
      *(_Float16*)(smem + h0w + w0off + r * 400 + 256) = (_Float16)v;  // h_prev
    }
  }
  __syncthreads();                              // h_prev(t) + OB visible

  // === coalesced flush every other step: 2 t-steps x 16 rows x 64 j ===
  // Store retires during next step's layer-0 (no barrier-adjacent drain).
  if (P) {
    f32x4 vv = *(const f32x4*)(smem + L_OB + v16);
    *(f32x4*)(outp0 + (unsigned)(t - 1) * 64u) = vv;
  }
}

__global__ __launch_bounds__(512, 2) void k_main(
    const float* __restrict__ z,
    const float* __restrict__ W_init_h, const float* __restrict__ b_init_h,
    const float* __restrict__ W_init_c, const float* __restrict__ b_init_c,
    const float* __restrict__ W_ih0, const float* __restrict__ W_hh0,
    const float* __restrict__ b_ih0, const float* __restrict__ b_hh0,
    const float* __restrict__ W_ih1, const float* __restrict__ W_hh1,
    const float* __restrict__ b_ih1, const float* __restrict__ b_hh1,
    const float* __restrict__ W_out, const float* __restrict__ b_out,
    float* __restrict__ out) {
  __shared__ __align__(16) unsigned char smem[L_TOT];
  const int tid = threadIdx.x;
  const int w = tid >> 6, l = tid & 63;
  const int l15 = l & 15, l4 = l >> 4;
  const int bl = blockIdx.x, b0 = bl << 4;
  const int col = 16 * w + l15;                 // owned gate/hidden col 0..127

  // ---------- prologue stage 1: fills ----------
  {
    // z tile -> AZ fp16: rows m=0..15, 256 cols, stride 528 B
    int zm = tid >> 5, zk = (tid & 31) * 8;
    *(h16x8*)(smem + L_AZ + zm * 528 + zk * 2) = cvt8h(z + (b0 + zm) * 256 + zk);
    // W_out -> per-wave frag stream: frag f=kc*4+wv, lane l holds
    // W_out[n=16*wv+(l&15)][k=kc*32+(l>>4)*8 .. +8]
    for (int i = tid; i < 1024; i += 512) {
      int li = i & 63, f = i >> 6;
      int kc = f >> 2, wv = f & 3;
      int n = 16 * wv + (li & 15), k0 = kc * 32 + ((li >> 4) & 3) * 8;
      *(h16x8*)(smem + L_WO + i * 16) = cvt8h(W_out + n * 128 + k0);
    }
    // compact bias tables
    *(float*)(smem + L_B1 + tid * 4) = b_ih1[tid] + b_hh1[tid];
    if (tid < 64) *(float*)(smem + L_BO + tid * 4) = b_out[tid];
    // zero h_prev cols (128..191) of H0 buffer 0
    if (tid < 256) {
      int r2 = tid >> 4, c2 = (tid & 15) * 4;
      h16x4 zz = {(_Float16)0, (_Float16)0, (_Float16)0, (_Float16)0};
      *(h16x4*)(smem + L_H0 + r2 * 400 + 256 + c2 * 2) = zz;
    }
  }
  __syncthreads();                              // AZ / WO / B1 / BO visible

  // ---------- prologue stage 2: MFMA prep GEMMs (reads AZ) ----------
  // xz[m][n] = z[m,:]·W_ih0[n,64:] + b_ih0[n]+b_hh0[n]   (n = g*128+col)
  // h/c init[m][layer*128+col] = z[m,:]·W_init_{h,c}[n,:] + b
  float c0i[4], c1i[4];
  f32x4 xza[4];
  {
    f32x4 ha[2], ca[2];
#pragma unroll
    for (int g = 0; g < 4; ++g) {
      float b = b_ih0[g * 128 + col] + b_hh0[g * 128 + col];
      f32x4 a = {b, b, b, b}; xza[g] = a;
    }
#pragma unroll
    for (int layer = 0; layer < 2; ++layer) {
      float bh = b_init_h[layer * 128 + col];
      float bc = b_init_c[layer * 128 + col];
      f32x4 ah = {bh, bh, bh, bh}; ha[layer] = ah;
      f32x4 ac = {bc, bc, bc, bc}; ca[layer] = ac;
    }
#pragma unroll
    for (int kc = 0; kc < 8; ++kc) {
      h16x8 az = *(const h16x8*)(smem + L_AZ + l15 * 528 + kc * 64 + l4 * 16);
      int kofs = kc * 32 + l4 * 8;
#pragma unroll
      for (int g = 0; g < 4; ++g) {
        h16x8 bz = cvt8h(W_ih0 + (g * 128 + col) * 320 + 64 + kofs);
        xza[g] = __builtin_amdgcn_mfma_f32_16x16x32_f16(az, bz, xza[g], 0, 0, 0);
      }
#pragma unroll
      for (int layer = 0; layer < 2; ++layer) {
        h16x8 bh = cvt8h(W_init_h + (layer * 128 + col) * 256 + kofs);
        ha[layer] = __builtin_amdgcn_mfma_f32_16x16x32_f16(az, bh, ha[layer], 0, 0, 0);
        h16x8 bc = cvt8h(W_init_c + (layer * 128 + col) * 256 + kofs);
        ca[layer] = __builtin_amdgcn_mfma_f32_16x16x32_f16(az, bc, ca[layer], 0, 0, 0);
      }
    }
    // h-init -> H0/H1 buffer 0 ; c stays in registers
#pragma unroll
    for (int r = 0; r < 4; ++r) {
      int m = l4 * 4 + r;
      *(_Float16*)(smem + L_H0 + m * 400 + col * 2) = (_Float16)ha[0][r];
      *(_Float16*)(smem + L_H1 + m * 272 + col * 2) = (_Float16)ha[1][r];
    }
#pragma unroll
    for (int r = 0; r < 4; ++r) { c0i[r] = ca[0][r]; c1i[r] = ca[1][r]; }
  }
  __syncthreads();                              // all AZ reads done
  // xz -> LDS fp16 (overwrites AZ region — safe after barrier)
#pragma unroll
  for (int g = 0; g < 4; ++g) {
    _Float16 t[4];
#pragma unroll
    for (int r = 0; r < 4; ++r) t[r] = (_Float16)xza[g][r];
    *(h16x4*)(smem + L_XZ + g * 4096 + tid * 8) = *(h16x4*)t;
  }

  // ---------- persistent weights into VGPR B-frags (fp16) ----------
  // L0 (K=192): k<128 -> W_hh0[n][k] (h0_old); k in [128,192) -> W_ih0[n][k-128] (h_prev)
  // L1 (K=256): k<128 -> W_ih1[n][k] (h0_new); k>=128 -> W_hh1[n][k-128] (h1_old)
  h16x8 wf[56];
#pragma unroll
  for (int kc = 0; kc < 6; ++kc)
#pragma unroll
    for (int g = 0; g < 4; ++g) {
      int n = g * 128 + col, k0 = kc * 32 + l4 * 8;
      const float* src = (k0 < 128) ? (W_hh0 + n * 128 + k0)
                                    : (W_ih0 + n * 320 + (k0 - 128));
      wf[kc * 4 + g] = cvt8h(src);
    }
#pragma unroll
  for (int kc = 0; kc < 8; ++kc)
#pragma unroll
    for (int g = 0; g < 4; ++g) {
      int n = g * 128 + col, k0 = kc * 32 + l4 * 8;
      const float* src = (k0 < 128) ? (W_ih1 + n * 128 + k0)
                                    : (W_hh1 + n * 128 + (k0 - 128));
      wf[24 + kc * 4 + g] = cvt8h(src);
    }

  f32x4 c0r, c1r;
#pragma unroll
  for (int r = 0; r < 4; ++r) { c0r[r] = c0i[r]; c1r[r] = c1i[r]; }

  // per-lane LDS offsets (affine in tid — cheap for regalloc to remat)
  const int a0off = l15 * 400 + l4 * 16;        // A-frag read within H0 buf
  const int a1off = l15 * 272 + l4 * 16;        // A-frag read within H1 buf
  const int xzoff = tid * 8;                    // XZ h16x4 (+g*4096)
  const int v16   = tid * 16;                   // WO frag read / OB flush read
  const int w0off = (l4 * 4) * 400 + col * 2;   // h0 write (+r*400)
  const int w1off = (l4 * 4) * 272 + col * 2;   // h1 write (+r*272)
  const int oboff = (l4 * 4) * 512 + col * 4;   // OB write (+r*512, +P*256)
  float* outp0 = out + (unsigned long long)(b0 + (tid >> 5)) * 65536ull +
                 ((tid * 4) & 127);
  __syncthreads();                              // h-init / xz visible

  // ---------- time loop (unrolled x2: compile-time ping-pong) ----------
  for (int t2 = 0; t2 < 1024; t2 += 2) {
    lstm_step<0>(smem, wf, c0r, c1r, a0off, a1off, xzoff, v16,
                 w0off, w1off, oboff, col, w, t2, outp0);
    lstm_step<1>(smem, wf, c0r, c1r, a0off, a1off, xzoff, v16,
                 w0off, w1off, oboff, col, w, t2 + 1, outp0);
  }
}

// ---------------- launch ----------------
extern "C" void kernel_launch(void* const* d_in, const int* in_sizes, int n_in,
                              void* d_out, int out_size, void* d_ws, size_t ws_size,
                              hipStream_t stream) {
  (void)in_sizes; (void)n_in; (void)out_size; (void)d_ws; (void)ws_size;
  const float* z        = (const float*)d_in[0];
  // d_in[1] = seq_len (int scalar) == 1024, hardcoded
  const float* W_init_h = (const float*)d_in[2];
  const float* b_init_h = (const float*)d_in[3];
  const float* W_init_c = (const float*)d_in[4];
  const float* b_init_c = (const float*)d_in[5];
  const float* W_ih0 = (const float*)d_in[6];
  const float* W_hh0 = (const float*)d_in[7];
  const float* b_ih0 = (const float*)d_in[8];
  const float* b_hh0 = (const float*)d_in[9];
  const float* W_ih1 = (const float*)d_in[10];
  const float* W_hh1 = (const float*)d_in[11];
  const float* b_ih1 = (const float*)d_in[12];
  const float* b_hh1 = (const float*)d_in[13];
  const float* W_out = (const float*)d_in[14];
  const float* b_out = (const float*)d_in[15];
  float* out = (float*)d_out;

  k_main<<<dim3(32), dim3(512), 0, stream>>>(
      z, W_init_h, b_init_h, W_init_c, b_init_c,
      W_ih0, W_hh0, b_ih0, b_hh0, W_ih1, W_hh1, b_ih1, b_hh1,
      W_out, b_out, out);
}